// Round 1
// baseline (173.381 us; speedup 1.0000x reference)
//
#include <hip/hip_runtime.h>
#include <hip/hip_bf16.h>

#define CC 256
#define NN 4096
#define CQ 32
#define LOG2E 1.4426950408889634f

using short8 = __attribute__((ext_vector_type(8))) short;
using f32x4  = __attribute__((ext_vector_type(4))) float;

static __device__ __forceinline__ short f2bf(float f) {
  __hip_bfloat16 h = __float2bfloat16(f);
  return *reinterpret_cast<short*>(&h);
}

// ---------------------------------------------------------------------------
// Kernel 0: build Wf = W (Wq|Wk|Wv rows concat, 320x256) in FRAG-LINEAR bf16
// layout: Wf[((tile*8 + kc)*64 + lane)*8 + j] = W[tile*16 + (lane&15)]
//                                               [kc*32 + (lane>>4)*8 + j]
// so a wave's A-frag load in qkv is one contiguous 1 KB read.
// ---------------------------------------------------------------------------
__global__ __launch_bounds__(256) void prep_kernel(
    const float* __restrict__ Wq, const float* __restrict__ Wk,
    const float* __restrict__ Wv, __hip_bfloat16* __restrict__ Wf)
{
  int t = blockIdx.x*256 + threadIdx.x;          // 0..10239
  int lane = t & 63, frag = t >> 6;              // frag = tile*8 + kc
  int tile = frag >> 3, kc = frag & 7;
  int l15 = lane & 15, quad = lane >> 4;
  int R = tile*16 + l15;                         // global output row 0..319
  int k0 = kc*32 + quad*8;
  const float* src;
  if (R < 32)       src = Wq + (size_t)R*CC + k0;
  else if (R < 64)  src = Wk + (size_t)(R-32)*CC + k0;
  else              src = Wv + (size_t)(R-64)*CC + k0;
  float4 a = *(const float4*)(src);
  float4 c = *(const float4*)(src + 4);
  short8 o;
  o[0]=f2bf(a.x); o[1]=f2bf(a.y); o[2]=f2bf(a.z); o[3]=f2bf(a.w);
  o[4]=f2bf(c.x); o[5]=f2bf(c.y); o[6]=f2bf(c.z); o[7]=f2bf(c.w);
  *reinterpret_cast<short8*>(reinterpret_cast<short*>(Wf) + (size_t)t*8) = o;
}

// ---------------------------------------------------------------------------
// Kernel 1: QKV via MFMA, x-stationary.  512 threads (8 waves), grid 64x4
// = 256 blocks = 8 waves/CU = 2/SIMD.  Stage x[256c x 64n] -> LDS bf16
// [n][c]; wave w computes r-tiles {2w, 2w+1} (+ tile 16+w for w<4).
// A-frags are contiguous 1KB loads from frag-linear Wf.  v output repacked
// via per-wave LDS -> coalesced 16B stores.
// ---------------------------------------------------------------------------
__global__ __launch_bounds__(512, 2) void qkv_kernel(
    const float* __restrict__ x, const __hip_bfloat16* __restrict__ Wf,
    const float* __restrict__ bq, const float* __restrict__ bk,
    const float* __restrict__ bv,
    __hip_bfloat16* __restrict__ qb, __hip_bfloat16* __restrict__ kb,
    __hip_bfloat16* __restrict__ vb)
{
  const int b  = blockIdx.y;
  const int n0 = blockIdx.x * 64;
  const int tid = threadIdx.x;
  const int lane = tid & 63;
  const int w = __builtin_amdgcn_readfirstlane(tid >> 6);  // wave 0..7
  const int l15 = lane & 15, quad = lane >> 4;

  __shared__ __align__(16) short Xs[64][264];     // [n][c] bf16, 33792 B
  __shared__ __align__(16) short Vr[8][16][72];   // per-wave repack, 18432 B

  // ---- stage x tile: thread covers n = tid&63, 8-c runs ----
  const int sn = tid & 63, cg8 = tid >> 6;
  const float* xcol = x + (size_t)b*CC*NN + n0 + sn;
#pragma unroll
  for (int it = 0; it < 4; it++) {
    int cbase = it*64 + cg8*8;
    float v[8];
#pragma unroll
    for (int j = 0; j < 8; j++) v[j] = xcol[(size_t)(cbase + j)*NN];
    short8 sv;
#pragma unroll
    for (int j = 0; j < 8; j++) sv[j] = f2bf(v[j]);
    *reinterpret_cast<short8*>(&Xs[sn][cbase]) = sv;
  }
  __syncthreads();

  const short* wfp = reinterpret_cast<const short*>(Wf);

#define QKV_TILE(T) { \
    const int t_ = (T); \
    short8 Af[8]; \
    _Pragma("unroll") \
    for (int kc = 0; kc < 8; kc++) \
      Af[kc] = *(const short8*)(wfp + ((size_t)(t_*8 + kc)*64 + lane)*8); \
    f32x4 ac0 = {0.f,0.f,0.f,0.f}, ac1 = {0.f,0.f,0.f,0.f}; \
    f32x4 ac2 = {0.f,0.f,0.f,0.f}, ac3 = {0.f,0.f,0.f,0.f}; \
    _Pragma("unroll") \
    for (int kc = 0; kc < 8; kc++) { \
      short8 B0 = *(const short8*)(&Xs[     l15][kc*32 + quad*8]); \
      short8 B1 = *(const short8*)(&Xs[16 + l15][kc*32 + quad*8]); \
      short8 B2 = *(const short8*)(&Xs[32 + l15][kc*32 + quad*8]); \
      short8 B3 = *(const short8*)(&Xs[48 + l15][kc*32 + quad*8]); \
      ac0 = __builtin_amdgcn_mfma_f32_16x16x32_bf16(Af[kc], B0, ac0, 0,0,0); \
      ac1 = __builtin_amdgcn_mfma_f32_16x16x32_bf16(Af[kc], B1, ac1, 0,0,0); \
      ac2 = __builtin_amdgcn_mfma_f32_16x16x32_bf16(Af[kc], B2, ac2, 0,0,0); \
      ac3 = __builtin_amdgcn_mfma_f32_16x16x32_bf16(Af[kc], B3, ac3, 0,0,0); \
    } \
    if (t_ < 2) { \
      int d0 = t_*16; \
      _Pragma("unroll") \
      for (int r = 0; r < 4; r++) { \
        int d = d0 + quad*4 + r; float bb = bq[d]; \
        qb[(size_t)b*NN*CQ + (size_t)(n0      + l15)*CQ + d] = __float2bfloat16(LOG2E*(ac0[r] + bb)); \
        qb[(size_t)b*NN*CQ + (size_t)(n0 + 16 + l15)*CQ + d] = __float2bfloat16(LOG2E*(ac1[r] + bb)); \
        qb[(size_t)b*NN*CQ + (size_t)(n0 + 32 + l15)*CQ + d] = __float2bfloat16(LOG2E*(ac2[r] + bb)); \
        qb[(size_t)b*NN*CQ + (size_t)(n0 + 48 + l15)*CQ + d] = __float2bfloat16(LOG2E*(ac3[r] + bb)); \
      } \
    } else if (t_ < 4) { \
      int d0 = (t_-2)*16; \
      _Pragma("unroll") \
      for (int r = 0; r < 4; r++) { \
        int d = d0 + quad*4 + r; float bb = bk[d]; \
        kb[(size_t)b*NN*CQ + (size_t)(n0      + l15)*CQ + d] = __float2bfloat16(ac0[r] + bb); \
        kb[(size_t)b*NN*CQ + (size_t)(n0 + 16 + l15)*CQ + d] = __float2bfloat16(ac1[r] + bb); \
        kb[(size_t)b*NN*CQ + (size_t)(n0 + 32 + l15)*CQ + d] = __float2bfloat16(ac2[r] + bb); \
        kb[(size_t)b*NN*CQ + (size_t)(n0 + 48 + l15)*CQ + d] = __float2bfloat16(ac3[r] + bb); \
      } \
    } else { \
      int rv0 = (t_-4)*16; \
      _Pragma("unroll") \
      for (int r = 0; r < 4; r++) { \
        float bb = bv[rv0 + quad*4 + r]; \
        Vr[w][quad*4 + r][     l15] = f2bf(ac0[r] + bb); \
        Vr[w][quad*4 + r][16 + l15] = f2bf(ac1[r] + bb); \
        Vr[w][quad*4 + r][32 + l15] = f2bf(ac2[r] + bb); \
        Vr[w][quad*4 + r][48 + l15] = f2bf(ac3[r] + bb); \
      } \
      int row = lane >> 2, cb = (lane & 3)*16; \
      short8 t0 = *(const short8*)(&Vr[w][row][cb]); \
      short8 t1 = *(const short8*)(&Vr[w][row][cb + 8]); \
      *(short8*)(vb + ((size_t)b*CC + rv0 + row)*NN + n0 + cb)     = t0; \
      *(short8*)(vb + ((size_t)b*CC + rv0 + row)*NN + n0 + cb + 8) = t1; \
    } }

  QKV_TILE(2*w);
  QKV_TILE(2*w + 1);
  if (w < 4) { QKV_TILE(16 + w); }
#undef QKV_TILE
}

// ---------------------------------------------------------------------------
// Kernel 2: O = softmax(QK^T) V, epilogue gamma*O + x.  512 threads, 8 waves.
// v2: NO V LDS staging — V[b] (2 MB) is L2-resident on the batch's 2 XCDs,
// so V MFMA A-fragments are read directly from global into registers,
// prefetched one tile ahead (4x16B/lane, full 64B-line utilization).
// Ps double-buffered (2x9 KB) -> ONE barrier per tile.  Per iteration:
// issue V(T+1)/K(T+2) loads; ds_read ap from Ps[T&1]; compute S(T+1)+exp
// and write Ps[(T+1)&1] (register-only, hides ap latency); 16 PV MFMAs
// from registers; rotate; barrier.  Numerics bit-identical to v1 (same
// bf16 values, same accumulation order).  LDS 33 KB (was 46.6 KB).
// ---------------------------------------------------------------------------
__global__ __launch_bounds__(512, 2) void attn_kernel(
    const __hip_bfloat16* __restrict__ qb, const __hip_bfloat16* __restrict__ kb,
    const __hip_bfloat16* __restrict__ vb,
    const float* __restrict__ x, const float* __restrict__ gamma,
    float* __restrict__ out)
{
  const int Bk = blockIdx.x;
  const int b = (Bk & 7) >> 1;                       // 2 XCDs per batch
  const int n0 = ((Bk >> 3)*2 + (Bk & 1)) * 64;      // n-tile 0..63
  const int tid = threadIdx.x;
  const int lane = tid & 63;
  const int w = __builtin_amdgcn_readfirstlane(tid >> 6);   // 0..7
  const int sg = w & 3;                               // S row-group / c-strip
  const int mh = w >> 2;                              // m-half 0/1
  const int l15 = lane & 15, quad = lane >> 4;

  // 32 KB pool: first 18432 B overlaid as Ps[2][64][72] during the main loop,
  // full 32 KB used as f32 combine scratch after it.
  __shared__ __align__(16) float poolf[8192];
  __shared__ float Lbuf2[2][64];
  auto Ps = reinterpret_cast<short (*)[64][72]>(poolf);

  const short* qbase = (const short*)qb + (size_t)b*NN*CQ;
  const short* kbase = (const short*)kb + (size_t)b*NN*CQ;
  const short* vbase = (const short*)vb + (size_t)b*CC*NN;

  short8 aq = *(const short8*)(qbase + (size_t)(n0 + sg*16 + l15)*CQ + quad*8);

  // per-lane fragment pointers: V rows (c) strided NN, K rows (m) strided CQ
  const short* vp0 = vbase + (size_t)(sg*64 +      l15)*NN + mh*32 + quad*8;
  const short* vp1 = vp0 + (size_t)16*NN;
  const short* vp2 = vp0 + (size_t)32*NN;
  const short* vp3 = vp0 + (size_t)48*NN;
  const short* kp0 = kbase + (size_t)(mh*32 +      l15)*CQ + quad*8;
  const short* kp1 = kbase + (size_t)(mh*32 + 16 + l15)*CQ + quad*8;

  const f32x4 z = {0.f,0.f,0.f,0.f};
  f32x4 acc[4][4];
#pragma unroll
  for (int cg = 0; cg < 4; cg++)
#pragma unroll
    for (int ng = 0; ng < 4; ng++) acc[cg][ng] = z;
  float lsum[4] = {0.f,0.f,0.f,0.f};

  // ---- prologue: K(0), V(0); S(0) -> Ps[0]; preload K(1) ----
  short8 kf0 = *(const short8*)(kp0);
  short8 kf1 = *(const short8*)(kp1);
  short8 vf0 = *(const short8*)(vp0);
  short8 vf1 = *(const short8*)(vp1);
  short8 vf2 = *(const short8*)(vp2);
  short8 vf3 = *(const short8*)(vp3);
  {
    f32x4 s0 = __builtin_amdgcn_mfma_f32_16x16x32_bf16(aq, kf0, z, 0,0,0);
    f32x4 s1 = __builtin_amdgcn_mfma_f32_16x16x32_bf16(aq, kf1, z, 0,0,0);
#pragma unroll
    for (int r = 0; r < 4; r++) {
      float e0 = __builtin_amdgcn_exp2f(s0[r]);
      float e1 = __builtin_amdgcn_exp2f(s1[r]);
      lsum[r] += e0 + e1;
      Ps[0][sg*16 + quad*4 + r][mh*32 +      l15] = f2bf(e0);
      Ps[0][sg*16 + quad*4 + r][mh*32 + 16 + l15] = f2bf(e1);
    }
  }
  kf0 = *(const short8*)(kp0 + 64*CQ);   // K(1)
  kf1 = *(const short8*)(kp1 + 64*CQ);
  __syncthreads();

  for (int T = 0; T < 64; T++) {
    // prefetch V(T+1) and K(T+2) (clamped re-load of last tile is unused)
    const int Tn = (T < 63) ? T + 1 : 63;
    const int Tk = (T < 62) ? T + 2 : 63;
    short8 nv0 = *(const short8*)(vp0 + Tn*64);
    short8 nv1 = *(const short8*)(vp1 + Tn*64);
    short8 nv2 = *(const short8*)(vp2 + Tn*64);
    short8 nv3 = *(const short8*)(vp3 + Tn*64);
    short8 nk0 = *(const short8*)(kp0 + (size_t)Tk*64*CQ);
    short8 nk1 = *(const short8*)(kp1 + (size_t)Tk*64*CQ);

    const int pb = T & 1;
    // ap reads for tile T (ready since last barrier)
    short8 ap0 = *(const short8*)(&Ps[pb][     l15][mh*32 + quad*8]);
    short8 ap1 = *(const short8*)(&Ps[pb][16 + l15][mh*32 + quad*8]);
    short8 ap2 = *(const short8*)(&Ps[pb][32 + l15][mh*32 + quad*8]);
    short8 ap3 = *(const short8*)(&Ps[pb][48 + l15][mh*32 + quad*8]);

    // S(T+1) + exp + Ps[pb^1] writes — independent of ap, fills its latency
    if (T < 63) {
      f32x4 s0 = __builtin_amdgcn_mfma_f32_16x16x32_bf16(aq, kf0, z, 0,0,0);
      f32x4 s1 = __builtin_amdgcn_mfma_f32_16x16x32_bf16(aq, kf1, z, 0,0,0);
#pragma unroll
      for (int r = 0; r < 4; r++) {
        float e0 = __builtin_amdgcn_exp2f(s0[r]);
        float e1 = __builtin_amdgcn_exp2f(s1[r]);
        lsum[r] += e0 + e1;
        Ps[pb^1][sg*16 + quad*4 + r][mh*32 +      l15] = f2bf(e0);
        Ps[pb^1][sg*16 + quad*4 + r][mh*32 + 16 + l15] = f2bf(e1);
      }
    }

    // PV(T): V fragments already in registers
    acc[0][0] = __builtin_amdgcn_mfma_f32_16x16x32_bf16(vf0, ap0, acc[0][0], 0,0,0);
    acc[0][1] = __builtin_amdgcn_mfma_f32_16x16x32_bf16(vf0, ap1, acc[0][1], 0,0,0);
    acc[0][2] = __builtin_amdgcn_mfma_f32_16x16x32_bf16(vf0, ap2, acc[0][2], 0,0,0);
    acc[0][3] = __builtin_amdgcn_mfma_f32_16x16x32_bf16(vf0, ap3, acc[0][3], 0,0,0);
    acc[1][0] = __builtin_amdgcn_mfma_f32_16x16x32_bf16(vf1, ap0, acc[1][0], 0,0,0);
    acc[1][1] = __builtin_amdgcn_mfma_f32_16x16x32_bf16(vf1, ap1, acc[1][1], 0,0,0);
    acc[1][2] = __builtin_amdgcn_mfma_f32_16x16x32_bf16(vf1, ap2, acc[1][2], 0,0,0);
    acc[1][3] = __builtin_amdgcn_mfma_f32_16x16x32_bf16(vf1, ap3, acc[1][3], 0,0,0);
    acc[2][0] = __builtin_amdgcn_mfma_f32_16x16x32_bf16(vf2, ap0, acc[2][0], 0,0,0);
    acc[2][1] = __builtin_amdgcn_mfma_f32_16x16x32_bf16(vf2, ap1, acc[2][1], 0,0,0);
    acc[2][2] = __builtin_amdgcn_mfma_f32_16x16x32_bf16(vf2, ap2, acc[2][2], 0,0,0);
    acc[2][3] = __builtin_amdgcn_mfma_f32_16x16x32_bf16(vf2, ap3, acc[2][3], 0,0,0);
    acc[3][0] = __builtin_amdgcn_mfma_f32_16x16x32_bf16(vf3, ap0, acc[3][0], 0,0,0);
    acc[3][1] = __builtin_amdgcn_mfma_f32_16x16x32_bf16(vf3, ap1, acc[3][1], 0,0,0);
    acc[3][2] = __builtin_amdgcn_mfma_f32_16x16x32_bf16(vf3, ap2, acc[3][2], 0,0,0);
    acc[3][3] = __builtin_amdgcn_mfma_f32_16x16x32_bf16(vf3, ap3, acc[3][3], 0,0,0);

    // rotate prefetched registers
    vf0 = nv0; vf1 = nv1; vf2 = nv2; vf3 = nv3;
    kf0 = nk0; kf1 = nk1;

    // one barrier/tile: publishes Ps[pb^1] writes, and guarantees this
    // tile's Ps[pb] reads complete before iteration T+1 overwrites it.
    __syncthreads();
  }

  // ---- L: reduce over l15, publish per m-half ----
#pragma unroll
  for (int r = 0; r < 4; r++) {
    float s = lsum[r];
    s += __shfl_xor(s, 1); s += __shfl_xor(s, 2);
    s += __shfl_xor(s, 4); s += __shfl_xor(s, 8);
    if (l15 == 0) Lbuf2[mh][sg*16 + quad*4 + r] = s;
  }

  // ---- combine mh halves of acc via LDS (2 rounds of 2 c-strips) ----
  __syncthreads();
#pragma unroll
  for (int g = 0; g < 2; g++) {
    if (mh == 1 && (sg >> 1) == g) {
#pragma unroll
      for (int cg = 0; cg < 4; cg++)
#pragma unroll
        for (int ng = 0; ng < 4; ng++)
#pragma unroll
          for (int r = 0; r < 4; r++)
            poolf[(sg & 1)*4096 + (cg*16 + quad*4 + r)*64 + ng*16 + l15] = acc[cg][ng][r];
    }
    __syncthreads();
    if (mh == 0 && (sg >> 1) == g) {
#pragma unroll
      for (int cg = 0; cg < 4; cg++)
#pragma unroll
        for (int ng = 0; ng < 4; ng++)
#pragma unroll
          for (int r = 0; r < 4; r++)
            acc[cg][ng][r] += poolf[(sg & 1)*4096 + (cg*16 + quad*4 + r)*64 + ng*16 + l15];
    }
    __syncthreads();
  }

  // ---- epilogue (mh==0 waves): out = gamma*O/l + x, coalesced rows ----
  if (mh == 0) {
    const float gm = gamma[0];
    float Lv[4];
#pragma unroll
    for (int ng = 0; ng < 4; ng++)
      Lv[ng] = 1.0f / (Lbuf2[0][ng*16 + l15] + Lbuf2[1][ng*16 + l15]);
#pragma unroll
    for (int cg = 0; cg < 4; cg++) {
#pragma unroll
      for (int ng = 0; ng < 4; ng++) {
#pragma unroll
        for (int r = 0; r < 4; r++) {
          size_t idx = ((size_t)b*CC + sg*64 + cg*16 + quad*4 + r)*NN + n0 + ng*16 + l15;
          out[idx] = gm * acc[cg][ng][r] * Lv[ng] + x[idx];
        }
      }
    }
  }
}

// ---------------------------------------------------------------------------
extern "C" void kernel_launch(void* const* d_in, const int* in_sizes, int n_in,
                              void* d_out, int out_size, void* d_ws, size_t ws_size,
                              hipStream_t stream) {
  const float* x     = (const float*)d_in[0];
  const float* Wq    = (const float*)d_in[1];
  const float* bq    = (const float*)d_in[2];
  const float* Wk    = (const float*)d_in[3];
  const float* bk    = (const float*)d_in[4];
  const float* Wv    = (const float*)d_in[5];
  const float* bv    = (const float*)d_in[6];
  const float* gamma = (const float*)d_in[7];
  float* out = (float*)d_out;

  char* ws = (char*)d_ws;
  if (ws_size < (11u << 20)) return;
  __hip_bfloat16* qb = (__hip_bfloat16*)(ws);                 // [B][N][32]  1 MB
  __hip_bfloat16* kb = (__hip_bfloat16*)(ws + (1u << 20));    // [B][N][32]  1 MB
  __hip_bfloat16* vb = (__hip_bfloat16*)(ws + (2u << 20));    // [B][C][N]   8 MB
  __hip_bfloat16* Wf = (__hip_bfloat16*)(ws + (10u << 20));   // frag-linear 160 KB

  prep_kernel<<<dim3(40), 256, 0, stream>>>(Wq, Wk, Wv, Wf);
  qkv_kernel<<<dim3(64, 4), 512, 0, stream>>>(x, Wf, bq, bk, bv, qb, kb, vb);
  attn_kernel<<<dim3(256), 512, 0, stream>>>(qb, kb, vb, x, gamma, out);
}